// Round 8
// baseline (16.129 us; speedup 1.0000x reference)
//
#include <hip/hip_runtime.h>
#include <hip/hip_bf16.h>
#include <math.h>

// HyperbolicDistanceHead: out[r][c] = -(2/sqrt(c))*atanh(clip(sqrt(c)*||mobius(-x,p)||, 0, 1-1e-5))
// B=128, C=4096, D=1024, c=0.5.
//  K1: x fp32 -> xb bf16 in MFMA-A-FRAGMENT order ([panel][t][lane] 16B words,
//      panel = 16 rows, t = K/32 step) + exact fp32 x2[128]. LDS transpose, 8 blocks.
//  K2: 512 blocks x 256 thr (2 blocks/CU); block = 64 rows x 16 cols; wave = 16x16
//      full-K (no combine). A streams coalesced bf16 from xb straight to MFMA regs
//      (no LDS). p: fp32 reg-stage -> cvt -> XOR-swz LDS dbuf (r7-proven), p2 fused.
//      BK=128 x 8 chunks, 1 barrier/chunk, T14 issue-early/write-late.

#define DDIM 1024
#define CDIM 4096
#define BDIM 128

using f32x4  = __attribute__((ext_vector_type(4))) float;
using bf16x8 = __attribute__((ext_vector_type(8))) short;

__device__ inline ushort toBfU(float f) {
  __hip_bfloat16 h = __float2bfloat16(f);
  return *reinterpret_cast<ushort*>(&h);
}

// ---------------- K1: x -> fragment-ordered bf16 + exact row sumsq ----------------
// 8 blocks x 512 thr; block = one 16-row panel. LDS bounce for transpose.
__global__ __launch_bounds__(512) void x_frag(
    const float* __restrict__ x, ushort* __restrict__ xb, float* __restrict__ x2) {
  __shared__ __align__(16) char lds[16 * 2048];   // [row][1024 bf16, XOR-swz]
  __shared__ float wpart[8][8];                   // [wave][iter] partial ssq

  const int tid  = threadIdx.x;
  const int lane = tid & 63;
  const int w    = tid >> 6;
  const int qp   = blockIdx.x;                    // panel 0..7 (rows 16qp..+15)
  const float* xp = x + (size_t)qp * 16 * DDIM;

  const int h    = tid >> 8;                      // row parity (waves 0-3: h=0)
  const int kcol = (tid & 255) * 4;               // float col of this thread

  float sq[8];
  #pragma unroll
  for (int it = 0; it < 8; ++it) {
    const int row = it * 2 + h;
    const f32x4 v = *(const f32x4*)(xp + (size_t)row * DDIM + kcol);
    float a = v[0] * v[0];
    a = fmaf(v[1], v[1], a); a = fmaf(v[2], v[2], a); a = fmaf(v[3], v[3], a);
    sq[it] = a;
    ushort4 o = { toBfU(v[0]), toBfU(v[1]), toBfU(v[2]), toBfU(v[3]) };
    const int kb = kcol * 2;                      // byte col (8-aligned)
    *(ushort4*)&lds[row * 2048 + (kb ^ ((row & 7) << 4))] = o;
  }
  #pragma unroll
  for (int it = 0; it < 8; ++it) {
    float a = sq[it];
    #pragma unroll
    for (int off = 32; off > 0; off >>= 1) a += __shfl_xor(a, off, 64);
    if (lane == 0) wpart[w][it] = a;
  }
  __syncthreads();
  if (tid < 16) {
    const int hh = tid & 1, it = tid >> 1, wb = hh * 4;
    x2[qp * 16 + tid] =
        wpart[wb][it] + wpart[wb + 1][it] + wpart[wb + 2][it] + wpart[wb + 3][it];
  }
  // fragment write-out: word (t,l) = x[qp*16 + (l&15)][t*32 + (l>>4)*8 .. +7]
  #pragma unroll
  for (int i = 0; i < 4; ++i) {
    const int widx = tid + i * 512;               // 0..2047
    const int t = widx >> 6, l = widx & 63, row = l & 15;
    const int kb16 = t * 64 + (l >> 4) * 16;
    const bf16x8 v = *(const bf16x8*)&lds[row * 2048 + (kb16 ^ ((row & 7) << 4))];
    *(bf16x8*)((char*)xb + ((size_t)qp * 2048 + widx) * 16) = v;
  }
}

// ---------------- K2: GEMM, A from fragments, B via LDS ----------------
__global__ __launch_bounds__(256) void hyper_frag(
    const ushort* __restrict__ xb, const float* __restrict__ p,
    const float* __restrict__ x2a, float* __restrict__ out) {
  __shared__ __align__(16) char ps[2][4096];      // [buf][16 cols][256 B]
  __shared__ float p2s[16];
  __shared__ float x2l[64];

  const int tid  = threadIdx.x;
  const int lane = tid & 63;
  const int w    = __builtin_amdgcn_readfirstlane(tid >> 6);  // 0..3
  const int r15  = lane & 15, g = lane >> 4;

  // bijective XCD chunk swizzle (512 % 8 == 0)
  const int bid = blockIdx.x;
  const int swz = ((bid & 7) << 6) | (bid >> 3);
  const int cg = swz >> 1, rg = swz & 1;
  const int rbase = rg * 64, cbase = cg * 16;

  // A fragment stream: panel q = rg*4 + w; word (t, lane) at (q*2048 + t*64 + lane)*16 B
  const char* ga = (const char*)xb + ((size_t)(rg * 4 + w) * 2048 + lane) * 16;

  // p staging: col = tid>>4, k-octet o = tid&15
  const int col = tid >> 4, o = tid & 15;
  const float* gp = p + (size_t)(cbase + col) * DDIM + o * 8;
  const int pw = col * 256 + ((o ^ (col & 7)) << 4);

  f32x4 acc = {0.f, 0.f, 0.f, 0.f};
  float p2p = 0.f;
  f32x4 pa0, pa1;
  bf16x8 aA[2][4];   // [phase][step] — indices constant after full unroll

#define ISSUE_A(c, ph)                                                         \
  { _Pragma("unroll")                                                          \
    for (int s = 0; s < 4; ++s)                                                \
      aA[ph][s] = *(const bf16x8*)(ga + ((c) * 4 + s) * 1024); }

#define ISSUE_P(c)                                                             \
  { pa0 = *(const f32x4*)(gp + (c) * 128);                                     \
    pa1 = *(const f32x4*)(gp + (c) * 128 + 4); }

#define WRITE_P(buf)                                                           \
  { p2p = fmaf(pa0[0], pa0[0], p2p); p2p = fmaf(pa0[1], pa0[1], p2p);          \
    p2p = fmaf(pa0[2], pa0[2], p2p); p2p = fmaf(pa0[3], pa0[3], p2p);          \
    p2p = fmaf(pa1[0], pa1[0], p2p); p2p = fmaf(pa1[1], pa1[1], p2p);          \
    p2p = fmaf(pa1[2], pa1[2], p2p); p2p = fmaf(pa1[3], pa1[3], p2p);          \
    bf16x8 _t;                                                                 \
    _t[0] = (short)toBfU(pa0[0]); _t[1] = (short)toBfU(pa0[1]);                \
    _t[2] = (short)toBfU(pa0[2]); _t[3] = (short)toBfU(pa0[3]);                \
    _t[4] = (short)toBfU(pa1[0]); _t[5] = (short)toBfU(pa1[1]);                \
    _t[6] = (short)toBfU(pa1[2]); _t[7] = (short)toBfU(pa1[3]);                \
    *(bf16x8*)&ps[buf][pw] = _t; }

#define COMPUTE(buf, ph)                                                       \
  { _Pragma("unroll")                                                          \
    for (int s = 0; s < 4; ++s) {                                              \
      const int off = ((s * 4 + g) ^ (r15 & 7)) << 4;                          \
      const bf16x8 b = *(const bf16x8*)&ps[buf][r15 * 256 + off];              \
      acc = __builtin_amdgcn_mfma_f32_16x16x32_bf16(aA[ph][s], b, acc, 0, 0, 0); \
    } }

  // ---- prologue: chunk 0 staged; preload x2 tile
  if (tid < 64) x2l[tid] = x2a[rbase + tid];
  ISSUE_A(0, 0)
  ISSUE_P(0)
  WRITE_P(0)

  // ---- main: 8 chunks, 1 barrier each; issue-early, write-late (T14)
  #pragma unroll
  for (int c = 0; c < 8; ++c) {
    __syncthreads();                 // publish ps[c&1] (+ x2l on c==0)
    if (c < 7) { ISSUE_A(c + 1, (c + 1) & 1) ISSUE_P(c + 1) }
    COMPUTE(c & 1, c & 1)
    if (c < 7) WRITE_P((c + 1) & 1)
  }

  // ---- p2 reduce: 16-lane groups (lanes sharing a col)
  p2p += __shfl_xor(p2p, 8, 64);
  p2p += __shfl_xor(p2p, 4, 64);
  p2p += __shfl_xor(p2p, 2, 64);
  p2p += __shfl_xor(p2p, 1, 64);
  if ((lane & 15) == 0) p2s[col] = p2p;
  __syncthreads();

  // ---- epilogue: closed-form Poincare distance, c = 0.5
  const float p2 = p2s[r15];
  #pragma unroll
  for (int i = 0; i < 4; ++i) {
    // C-frag: col = lane&15, row = (lane>>4)*4 + i (verified m89 mapping)
    const int  rloc = (w << 4) + (g << 2) + i;     // block-local row
    const float dot = acc[i];                      // <x,p>; mdot = -dot
    const float x2  = x2l[rloc];
    const float A   = 1.0f - dot + 0.5f  * p2;     // 1 + 2c*mdot + c*p2
    const float Bc  = 1.0f - 0.5f * x2;            // 1 - c*x2
    const float den = 1.0f - dot + 0.25f * x2 * p2;
    float num2 = A * A * x2 - 2.0f * A * Bc * dot + Bc * Bc * p2;
    float m2   = fmaxf(num2, 0.0f) / fmaxf(den * den, 1e-15f);
    float arg  = fminf(0.7071067811865476f * sqrtf(m2 + 1e-15f), 0.99999f);
    out[(size_t)(rbase + rloc) * CDIM + cbase + r15] =
        -1.4142135623730951f * __logf((1.0f + arg) / (1.0f - arg));
  }
}

extern "C" void kernel_launch(void* const* d_in, const int* in_sizes, int n_in,
                              void* d_out, int out_size, void* d_ws, size_t ws_size,
                              hipStream_t stream) {
  const float* x = (const float*)d_in[0];   // [128,1024] fp32
  const float* p = (const float*)d_in[1];   // [4096,1024] fp32
  float* out = (float*)d_out;               // [128,4096] fp32

  // ws: xb fragment-ordered [8 panels][2048 words][16 B] = 256 KB | x2[128] f32
  ushort* xb = (ushort*)d_ws;
  float*  x2 = (float*)((char*)d_ws + (size_t)8 * 2048 * 16);

  x_frag<<<dim3(8), dim3(512), 0, stream>>>(x, xb, x2);
  hyper_frag<<<dim3(512), dim3(256), 0, stream>>>(xb, p, x2, out);
}